// Round 6
// baseline (618.123 us; speedup 1.0000x reference)
//
#include <hip/hip_runtime.h>
#include <hip/hip_bf16.h>
#include <hip/hip_fp16.h>
#include <math.h>

#define S_LEN   4096
#define B_SZ    32
#define D_DIM   64
#define L_LNK   13
#define NW_R    13
#define HF_W    128
#define HV_W    128
#define VOCAB_N 512
#define NC_N    2

#define STRIDE  512            // chord rows per thread-stride
#define NROW    8              // rows per thread
#define MIRROR  256            // mirrored rows (max LDS link offset)
#define BUFN    (S_LEN + MIRROR)
#define ZSCALE  (1.0f / 256.0f)   // fp16 range headroom (exact pow2)

typedef float vf4 __attribute__((ext_vector_type(4)));

// 4 fp16 values, 8-byte aligned so LDS access is ds_read_b64/ds_write_b64
struct alignas(8) h4 { __half2 a, b; };

__device__ __forceinline__ float gelu_erf(float x) {
    return 0.5f * x * (1.0f + erff(x * 0.70710678118654752440f));
}

// acc += c * z  with z fp16: each element is fmaf(f32, fpext(f16), f32),
// which the AMDGPU backend selects as a single v_fma_mix_f32 (no unpack).
__device__ __forceinline__ void fmamix4(vf4& acc, float c, h4 z) {
    acc.x = fmaf(c, __half2float(z.a.x), acc.x);
    acc.y = fmaf(c, __half2float(z.a.y), acc.y);
    acc.z = fmaf(c, __half2float(z.b.x), acc.z);
    acc.w = fmaf(c, __half2float(z.b.y), acc.w);
}

__device__ __forceinline__ h4 pack4h(vf4 v) {
    h4 r;
    r.a = __float22half2_rn(float2{v.x, v.y});
    r.b = __float22half2_rn(float2{v.z, v.w});
    return r;
}

__device__ __forceinline__ vf4 unpack4h(h4 z) {
    vf4 r;
    r.x = __half2float(z.a.x); r.y = __half2float(z.a.y);
    r.z = __half2float(z.b.x); r.w = __half2float(z.b.y);
    return r;
}

__device__ __forceinline__ void cvt2(unsigned int w, float& a, float& b) {
    __half2 h = *reinterpret_cast<__half2*>(&w);
    a = __half2float(h.x); b = __half2float(h.y);
}

// ---------------------------------------------------------------------------
// Kernel A: per-token tables (R1/R5 structure — max parallelism).
// F_table fp16, rows padded to 16 halves (32 B). Grid: 13*512 + 512 x 128.
// ---------------------------------------------------------------------------
__global__ __launch_bounds__(128)
void tables_kernel(const float* __restrict__ emb,
                   const float* __restrict__ fW1, const float* __restrict__ fb1,
                   const float* __restrict__ fW2, const float* __restrict__ fb2,
                   const float* __restrict__ vW1, const float* __restrict__ vb1,
                   const float* __restrict__ vW2, const float* __restrict__ vb2,
                   __half* __restrict__ F_table, float* __restrict__ V_table) {
    __shared__ float s_emb[D_DIM];
    __shared__ float s_H[HF_W];
    const int blk = blockIdx.x;
    const int tid = threadIdx.x;

    if (blk < NW_R * VOCAB_N) {
        const int k = blk >> 9;
        const int t = blk & (VOCAB_N - 1);
        if (tid < D_DIM) s_emb[tid] = emb[t * D_DIM + tid];
        __syncthreads();
        float acc = fb1[k * HF_W + tid];
        const float* w = fW1 + (size_t)k * D_DIM * HF_W + tid;
        #pragma unroll 8
        for (int d = 0; d < D_DIM; ++d) acc += s_emb[d] * w[d * HF_W];
        s_H[tid] = gelu_erf(acc);
        __syncthreads();
        if (tid < 16) {
            float o = 0.0f;
            if (tid < L_LNK) {
                o = fb2[k * L_LNK + tid];
                const float* w2 = fW2 + (size_t)k * HF_W * L_LNK + tid;
                #pragma unroll 8
                for (int h = 0; h < HF_W; ++h) o += s_H[h] * w2[h * L_LNK];
            }
            F_table[((size_t)(k * VOCAB_N + t)) * 16 + tid] = __float2half_rn(o);
        }
    } else {
        const int t = blk - NW_R * VOCAB_N;
        if (tid < D_DIM) s_emb[tid] = emb[t * D_DIM + tid];
        __syncthreads();
        float acc = vb1[tid];
        const float* w = vW1 + tid;
        #pragma unroll 8
        for (int d = 0; d < D_DIM; ++d) acc += s_emb[d] * w[d * HV_W];
        s_H[tid] = gelu_erf(acc);
        __syncthreads();
        if (tid < D_DIM) {
            float o = vb2[tid];
            const float* w2 = vW2 + tid;
            #pragma unroll 8
            for (int h = 0; h < HV_W; ++h) o += s_H[h] * w2[h * D_DIM];
            V_table[t * D_DIM + tid] = o;
        }
    }
}

// ---------------------------------------------------------------------------
// Kernel B (fused): blocks [0,64) = logits (scheduled first, hidden under
// chord); blocks [64,576) = chord sparse-multiply.
//
// Chord: 512 threads, thread t owns rows t+512j (j=0..7):
//  - offsets 0/512/1024/2048 from packed-fp16 register array zp[8].
//  - 9 LDS links (1..256) from mirrored double-buffered fp16 Zs -> b64 reads
//    with immediate offsets, ONE barrier per round.
//  - Z scaled by 1/256 (linear recurrence: scale V, rescale at output).
//  - F fp16 rows via SGPR base + voffset; coeffs converted once per row,
//    links consumed as v_fma_mix_f32.
// LDS 2*4352*8 = 69,632 B -> 2 blocks/CU -> 16 waves/CU.
// ---------------------------------------------------------------------------
__global__ __launch_bounds__(512, 4)
void fused_kernel(const int* __restrict__ tok,
                  const __half* __restrict__ F_table,
                  const float* __restrict__ V_table,
                  const float* __restrict__ finW,
                  const float* __restrict__ finb,
                  float* __restrict__ out,
                  float* __restrict__ Zout) {
    __shared__ h4 Zs[2][BUFN];
    const int blk = blockIdx.x;
    const int t = threadIdx.x;

    if (blk < B_SZ * NC_N) {
        // ---------------- logits branch ----------------
        const int b = blk >> 1;
        const int c = blk & 1;
        const float4* fin4 = (const float4*)(finW + (size_t)c * S_LEN * D_DIM);
        const float4* V4 = (const float4*)V_table;
        float acc = 0.0f;
        #pragma unroll
        for (int it = 0; it < 8; ++it) {
            const int s = t + it * 512;
            const int tk = tok[b * S_LEN + s];
            const float4* vp = V4 + tk * 16;
            const float4* fp = fin4 + s * 16;
            #pragma unroll
            for (int j = 0; j < 16; ++j) {
                float4 v = vp[j], f = fp[j];
                acc += v.x * f.x + v.y * f.y + v.z * f.z + v.w * f.w;
            }
        }
        #pragma unroll
        for (int o = 32; o > 0; o >>= 1) acc += __shfl_down(acc, o, 64);
        float* sp = (float*)&Zs[0][0];
        if ((t & 63) == 0) sp[t >> 6] = acc;
        __syncthreads();
        if (t == 0) {
            float s = finb[c];
            #pragma unroll
            for (int i = 0; i < 8; ++i) s += sp[i];
            out[b * NC_N + c] = s;
        }
        return;
    }

    // ---------------- chord branch ----------------
    const int cid = blk - B_SZ * NC_N;
    const int ds = cid & 15;        // dim slice
    const int b = cid >> 4;         // batch
    const vf4* V4 = (const vf4*)V_table;

    unsigned tokf[NROW];
    h4 Vp[NROW], zp[NROW];
    #pragma unroll
    for (int j = 0; j < NROW; ++j) {
        const int r = t + STRIDE * j;
        const int tk = tok[b * S_LEN + r];
        tokf[j] = (unsigned)tk * 32u;
        vf4 v = V4[tk * 16 + ds] * ZSCALE;
        h4 p = pack4h(v);
        Vp[j] = p; zp[j] = p;
        Zs[0][r] = p;
    }
    if (t < MIRROR) Zs[0][S_LEN + t] = zp[0];
    __syncthreads();

    int cur = 0;
    vf4 acc[NROW];
    #pragma unroll 1
    for (int k = 0; k < NW_R; ++k) {
        const char* Fk = (const char*)F_table + (size_t)k * (VOCAB_N * 32);
        const h4* Zc = Zs[cur];
        #pragma unroll
        for (int j = 0; j < NROW; ++j) {
            const int r = t + STRIDE * j;
            const char* Fr = Fk + tokf[j];
            uint4 u0 = *(const uint4*)Fr;                 // coeffs 0..7
            uint2 u1 = *(const uint2*)(Fr + 16);          // coeffs 8..11
            unsigned u2 = *(const unsigned*)(Fr + 24);    // coeff 12 (+pad)
            // coeff -> offset: c0:0 c1:1 c2:2 c3:4 c4:8 c5:16 c6:32 c7:64
            //                  c8:128 c9:256 c10:512 c11:1024 c12:2048
            float c0,c1,c2,c3,c4,c5,c6,c7,c8,c9,c10,c11,c12,cp;
            cvt2(u0.x,c0,c1);  cvt2(u0.y,c2,c3);
            cvt2(u0.z,c4,c5);  cvt2(u0.w,c6,c7);
            cvt2(u1.x,c8,c9);  cvt2(u1.y,c10,c11);
            cvt2(u2,c12,cp);   (void)cp;

            vf4 a = unpack4h(Vp[j]);                   // residual
            fmamix4(a, c0,  zp[j]);                    // off 0
            fmamix4(a, c10, zp[(j + 1) & 7]);          // off 512
            fmamix4(a, c11, zp[(j + 2) & 7]);          // off 1024
            fmamix4(a, c12, zp[(j + 4) & 7]);          // off 2048
            fmamix4(a, c1, Zc[r + 1]);
            fmamix4(a, c2, Zc[r + 2]);
            fmamix4(a, c3, Zc[r + 4]);
            fmamix4(a, c4, Zc[r + 8]);
            fmamix4(a, c5, Zc[r + 16]);
            fmamix4(a, c6, Zc[r + 32]);
            fmamix4(a, c7, Zc[r + 64]);
            fmamix4(a, c8, Zc[r + 128]);
            fmamix4(a, c9, Zc[r + 256]);
            acc[j] = a;
        }
        if (k < NW_R - 1) {
            h4* Zn = Zs[cur ^ 1];
            #pragma unroll
            for (int j = 0; j < NROW; ++j) {
                h4 p = pack4h(acc[j]);
                zp[j] = p;
                Zn[t + STRIDE * j] = p;
            }
            if (t < MIRROR) Zn[S_LEN + t] = zp[0];
        }
        __syncthreads();   // single barrier/round (double buffer -> no WAR)
        cur ^= 1;
    }

    #pragma unroll
    for (int j = 0; j < NROW; ++j) {
        const int r = t + STRIDE * j;
        vf4 o = acc[j] * 256.0f;       // undo ZSCALE
        *(vf4*)(Zout + (((size_t)b * S_LEN + r) << 6) + ds * 4) = o;
    }
}

extern "C" void kernel_launch(void* const* d_in, const int* in_sizes, int n_in,
                              void* d_out, int out_size, void* d_ws, size_t ws_size,
                              hipStream_t stream) {
    const int*   tok  = (const int*)d_in[0];
    const float* emb  = (const float*)d_in[1];
    const float* fW1  = (const float*)d_in[2];
    const float* fb1  = (const float*)d_in[3];
    const float* fW2  = (const float*)d_in[4];
    const float* fb2  = (const float*)d_in[5];
    const float* vW1  = (const float*)d_in[6];
    const float* vb1  = (const float*)d_in[7];
    const float* vW2  = (const float*)d_in[8];
    const float* vb2  = (const float*)d_in[9];
    const float* finW = (const float*)d_in[10];
    const float* finb = (const float*)d_in[11];

    float* out = (float*)d_out;          // (B, NC) = 64 floats
    float* Z   = out + B_SZ * NC_N;      // (B, S, D) fp32

    float*  V_table = (float*)d_ws;                         // 512*64 f32
    __half* F_table = (__half*)(V_table + VOCAB_N * D_DIM); // 13*512*16 f16

    tables_kernel<<<NW_R * VOCAB_N + VOCAB_N, 128, 0, stream>>>(
        emb, fW1, fb1, fW2, fb2, vW1, vb1, vW2, vb2, F_table, V_table);
    fused_kernel<<<B_SZ * NC_N + 16 * B_SZ, 512, 0, stream>>>(
        tok, F_table, V_table, finW, finb, out, Z);
}

// Round 7
// 610.888 us; speedup vs baseline: 1.0118x; 1.0118x over previous
//
#include <hip/hip_runtime.h>
#include <hip/hip_bf16.h>
#include <hip/hip_fp16.h>
#include <math.h>

#define S_LEN   4096
#define B_SZ    32
#define D_DIM   64
#define L_LNK   13
#define NW_R    13
#define HF_W    128
#define HV_W    128
#define VOCAB_N 512
#define NC_N    2

#define STRIDE  512            // chord rows per thread-stride
#define NROW    8              // rows per thread
#define MIRROR  256            // mirrored rows (max LDS link offset)
#define BUFN    (S_LEN + MIRROR)
#define ZSCALE  (1.0f / 256.0f)   // fp16 range headroom (exact pow2)

typedef float vf4 __attribute__((ext_vector_type(4)));

__device__ __forceinline__ float gelu_erf(float x) {
    return 0.5f * x * (1.0f + erff(x * 0.70710678118654752440f));
}

// acc += c * z, z = 4 packed fp16 in a uint2. __half2 only in scalar locals
// (register state arrays stay uint2 — struct arrays defeat SROA, see R6).
// fmaf(f32, fpext(f16), f32) selects to single v_fma_mix_f32.
__device__ __forceinline__ void fmamix4(vf4& acc, float c, uint2 z) {
    __half2 lo = *reinterpret_cast<__half2*>(&z.x);
    __half2 hi = *reinterpret_cast<__half2*>(&z.y);
    acc.x = fmaf(c, __half2float(lo.x), acc.x);
    acc.y = fmaf(c, __half2float(lo.y), acc.y);
    acc.z = fmaf(c, __half2float(hi.x), acc.z);
    acc.w = fmaf(c, __half2float(hi.y), acc.w);
}

__device__ __forceinline__ uint2 pack4h(vf4 v) {
    __half2 a = __float22half2_rn(float2{v.x, v.y});
    __half2 b = __float22half2_rn(float2{v.z, v.w});
    uint2 r;
    r.x = *reinterpret_cast<unsigned int*>(&a);
    r.y = *reinterpret_cast<unsigned int*>(&b);
    return r;
}

__device__ __forceinline__ vf4 unpack4h(uint2 z) {
    __half2 lo = *reinterpret_cast<__half2*>(&z.x);
    __half2 hi = *reinterpret_cast<__half2*>(&z.y);
    vf4 r;
    r.x = __half2float(lo.x); r.y = __half2float(lo.y);
    r.z = __half2float(hi.x); r.w = __half2float(hi.y);
    return r;
}

__device__ __forceinline__ void cvt2(unsigned int w, float& a, float& b) {
    __half2 h = *reinterpret_cast<__half2*>(&w);
    a = __half2float(h.x); b = __half2float(h.y);
}

// ---------------------------------------------------------------------------
// Kernel A: per-token tables (R1/R5 structure — max parallelism).
// F_table fp16, rows padded to 16 halves (32 B). Grid: 13*512 + 512 x 128.
// ---------------------------------------------------------------------------
__global__ __launch_bounds__(128)
void tables_kernel(const float* __restrict__ emb,
                   const float* __restrict__ fW1, const float* __restrict__ fb1,
                   const float* __restrict__ fW2, const float* __restrict__ fb2,
                   const float* __restrict__ vW1, const float* __restrict__ vb1,
                   const float* __restrict__ vW2, const float* __restrict__ vb2,
                   __half* __restrict__ F_table, float* __restrict__ V_table) {
    __shared__ float s_emb[D_DIM];
    __shared__ float s_H[HF_W];
    const int blk = blockIdx.x;
    const int tid = threadIdx.x;

    if (blk < NW_R * VOCAB_N) {
        const int k = blk >> 9;
        const int t = blk & (VOCAB_N - 1);
        if (tid < D_DIM) s_emb[tid] = emb[t * D_DIM + tid];
        __syncthreads();
        float acc = fb1[k * HF_W + tid];
        const float* w = fW1 + (size_t)k * D_DIM * HF_W + tid;
        #pragma unroll 8
        for (int d = 0; d < D_DIM; ++d) acc += s_emb[d] * w[d * HF_W];
        s_H[tid] = gelu_erf(acc);
        __syncthreads();
        if (tid < 16) {
            float o = 0.0f;
            if (tid < L_LNK) {
                o = fb2[k * L_LNK + tid];
                const float* w2 = fW2 + (size_t)k * HF_W * L_LNK + tid;
                #pragma unroll 8
                for (int h = 0; h < HF_W; ++h) o += s_H[h] * w2[h * L_LNK];
            }
            F_table[((size_t)(k * VOCAB_N + t)) * 16 + tid] = __float2half_rn(o);
        }
    } else {
        const int t = blk - NW_R * VOCAB_N;
        if (tid < D_DIM) s_emb[tid] = emb[t * D_DIM + tid];
        __syncthreads();
        float acc = vb1[tid];
        const float* w = vW1 + tid;
        #pragma unroll 8
        for (int d = 0; d < D_DIM; ++d) acc += s_emb[d] * w[d * HV_W];
        s_H[tid] = gelu_erf(acc);
        __syncthreads();
        if (tid < D_DIM) {
            float o = vb2[tid];
            const float* w2 = vW2 + tid;
            #pragma unroll 8
            for (int h = 0; h < HV_W; ++h) o += s_H[h] * w2[h * D_DIM];
            V_table[t * D_DIM + tid] = o;
        }
    }
}

// ---------------------------------------------------------------------------
// Kernel B (fused): blocks [0,64) = logits; blocks [64,576) = chord.
// Chord = R5's proven no-spill structure (uint2 register arrays, mirrored
// double-buffered LDS, 1 barrier/round), with Z in fp16*1/256 consumed by
// v_fma_mix_f32. LDS 2*4352*8 = 69,632 B -> 2 blocks/CU.
// ---------------------------------------------------------------------------
__global__ __launch_bounds__(512, 4)
void fused_kernel(const int* __restrict__ tok,
                  const __half* __restrict__ F_table,
                  const float* __restrict__ V_table,
                  const float* __restrict__ finW,
                  const float* __restrict__ finb,
                  float* __restrict__ out,
                  float* __restrict__ Zout) {
    __shared__ uint2 Zs[2][BUFN];
    const int blk = blockIdx.x;
    const int t = threadIdx.x;

    if (blk < B_SZ * NC_N) {
        // ---------------- logits branch ----------------
        const int b = blk >> 1;
        const int c = blk & 1;
        const float4* fin4 = (const float4*)(finW + (size_t)c * S_LEN * D_DIM);
        const float4* V4 = (const float4*)V_table;
        float acc = 0.0f;
        #pragma unroll
        for (int it = 0; it < 8; ++it) {
            const int s = t + it * 512;
            const int tk = tok[b * S_LEN + s];
            const float4* vp = V4 + tk * 16;
            const float4* fp = fin4 + s * 16;
            #pragma unroll
            for (int j = 0; j < 16; ++j) {
                float4 v = vp[j], f = fp[j];
                acc += v.x * f.x + v.y * f.y + v.z * f.z + v.w * f.w;
            }
        }
        #pragma unroll
        for (int o = 32; o > 0; o >>= 1) acc += __shfl_down(acc, o, 64);
        float* sp = (float*)&Zs[0][0];
        if ((t & 63) == 0) sp[t >> 6] = acc;
        __syncthreads();
        if (t == 0) {
            float s = finb[c];
            #pragma unroll
            for (int i = 0; i < 8; ++i) s += sp[i];
            out[b * NC_N + c] = s;
        }
        return;
    }

    // ---------------- chord branch ----------------
    const int cid = blk - B_SZ * NC_N;
    const int ds = cid & 15;        // dim slice
    const int b = cid >> 4;         // batch
    const vf4* V4 = (const vf4*)V_table;

    unsigned tokf[NROW];
    uint2 Vp[NROW], zp[NROW];
    #pragma unroll
    for (int j = 0; j < NROW; ++j) {
        const int r = t + STRIDE * j;
        const int tk = tok[b * S_LEN + r];
        tokf[j] = (unsigned)tk * 32u;
        vf4 v = V4[tk * 16 + ds] * ZSCALE;
        uint2 p = pack4h(v);
        Vp[j] = p; zp[j] = p;
        Zs[0][r] = p;
    }
    if (t < MIRROR) Zs[0][S_LEN + t] = zp[0];
    __syncthreads();

    int cur = 0;
    vf4 acc[NROW];
    #pragma unroll 1
    for (int k = 0; k < NW_R; ++k) {
        const char* Fk = (const char*)F_table + (size_t)k * (VOCAB_N * 32);
        const uint2* Zc = Zs[cur];
        #pragma unroll
        for (int j = 0; j < NROW; ++j) {
            const int r = t + STRIDE * j;
            const char* Fr = Fk + tokf[j];
            uint4 u0 = *(const uint4*)Fr;                 // coeffs 0..7
            uint2 u1 = *(const uint2*)(Fr + 16);          // coeffs 8..11
            unsigned u2 = *(const unsigned*)(Fr + 24);    // coeff 12 (+pad)
            // coeff -> offset: c0:0 c1:1 c2:2 c3:4 c4:8 c5:16 c6:32 c7:64
            //                  c8:128 c9:256 c10:512 c11:1024 c12:2048
            float c0,c1,c2,c3,c4,c5,c6,c7,c8,c9,c10,c11,c12,cp;
            cvt2(u0.x,c0,c1);  cvt2(u0.y,c2,c3);
            cvt2(u0.z,c4,c5);  cvt2(u0.w,c6,c7);
            cvt2(u1.x,c8,c9);  cvt2(u1.y,c10,c11);
            cvt2(u2,c12,cp);   (void)cp;

            vf4 a = unpack4h(Vp[j]);                   // residual
            fmamix4(a, c0,  zp[j]);                    // off 0
            fmamix4(a, c10, zp[(j + 1) & 7]);          // off 512
            fmamix4(a, c11, zp[(j + 2) & 7]);          // off 1024
            fmamix4(a, c12, zp[(j + 4) & 7]);          // off 2048
            fmamix4(a, c1, Zc[r + 1]);
            fmamix4(a, c2, Zc[r + 2]);
            fmamix4(a, c3, Zc[r + 4]);
            fmamix4(a, c4, Zc[r + 8]);
            fmamix4(a, c5, Zc[r + 16]);
            fmamix4(a, c6, Zc[r + 32]);
            fmamix4(a, c7, Zc[r + 64]);
            fmamix4(a, c8, Zc[r + 128]);
            fmamix4(a, c9, Zc[r + 256]);
            acc[j] = a;
        }
        if (k < NW_R - 1) {
            uint2* Zn = Zs[cur ^ 1];
            #pragma unroll
            for (int j = 0; j < NROW; ++j) {
                uint2 p = pack4h(acc[j]);
                zp[j] = p;
                Zn[t + STRIDE * j] = p;
            }
            if (t < MIRROR) Zn[S_LEN + t] = zp[0];
        }
        __syncthreads();   // single barrier/round (double buffer -> no WAR)
        cur ^= 1;
    }

    #pragma unroll
    for (int j = 0; j < NROW; ++j) {
        const int r = t + STRIDE * j;
        vf4 o = acc[j] * 256.0f;       // undo ZSCALE
        *(vf4*)(Zout + (((size_t)b * S_LEN + r) << 6) + ds * 4) = o;
    }
}

extern "C" void kernel_launch(void* const* d_in, const int* in_sizes, int n_in,
                              void* d_out, int out_size, void* d_ws, size_t ws_size,
                              hipStream_t stream) {
    const int*   tok  = (const int*)d_in[0];
    const float* emb  = (const float*)d_in[1];
    const float* fW1  = (const float*)d_in[2];
    const float* fb1  = (const float*)d_in[3];
    const float* fW2  = (const float*)d_in[4];
    const float* fb2  = (const float*)d_in[5];
    const float* vW1  = (const float*)d_in[6];
    const float* vb1  = (const float*)d_in[7];
    const float* vW2  = (const float*)d_in[8];
    const float* vb2  = (const float*)d_in[9];
    const float* finW = (const float*)d_in[10];
    const float* finb = (const float*)d_in[11];

    float* out = (float*)d_out;          // (B, NC) = 64 floats
    float* Z   = out + B_SZ * NC_N;      // (B, S, D) fp32

    float*  V_table = (float*)d_ws;                         // 512*64 f32
    __half* F_table = (__half*)(V_table + VOCAB_N * D_DIM); // 13*512*16 f16

    tables_kernel<<<NW_R * VOCAB_N + VOCAB_N, 128, 0, stream>>>(
        emb, fW1, fb1, fW2, fb2, vW1, vb1, vW2, vb2, F_table, V_table);
    fused_kernel<<<B_SZ * NC_N + 16 * B_SZ, 512, 0, stream>>>(
        tok, F_table, V_table, finW, finb, out, Z);
}